// Round 12
// baseline (482.090 us; speedup 1.0000x reference)
//
#include <hip/hip_runtime.h>
#include <hip/hip_bf16.h>

constexpr int DD = 128;   // hidden dim D
constexpr int AA = 64;    // attention dim A
constexpr int GG = 384;   // 3*D (GRU gates)
constexpr int XPAD = 136; // LDS X-tile row stride in shorts (128 + 8 pad)
constexpr int GTS = 192;  // gather-table row stride in shorts: 64 proj + 128 x

#define SLOPE_F 0.22916666666666666f
#define LNEPS   1e-5f

typedef __attribute__((ext_vector_type(8))) short short8;
typedef __attribute__((ext_vector_type(4))) float f32x4;

static __device__ __forceinline__ float wave_sum(float v){
#pragma unroll
  for (int off = 32; off > 0; off >>= 1) v += __shfl_xor(v, off, 64);
  return v;
}
static __device__ __forceinline__ float red16(float v){
#pragma unroll
  for (int off = 1; off < 16; off <<= 1) v += __shfl_xor(v, off, 64);
  return v;
}
static __device__ __forceinline__ float sigm(float x){ return 1.0f / (1.0f + __expf(-x)); }
static __device__ __forceinline__ float fast_tanh(float x){
  float ax = fabsf(x);
  float t = __expf(-2.0f * ax);
  float r = (1.0f - t) / (1.0f + t);
  return copysignf(r, x);
}
static __device__ __forceinline__ float rrelu_f(float x){ return x >= 0.0f ? x : SLOPE_F * x; }
static __device__ __forceinline__ short bf16b(float f){
  __hip_bfloat16 h = __float2bfloat16(f);
  return *reinterpret_cast<short*>(&h);
}
static __device__ __forceinline__ float b2f_lo(unsigned int x){
  return __uint_as_float(x << 16);
}
static __device__ __forceinline__ float b2f_hi(unsigned int x){
  return __uint_as_float(x & 0xffff0000u);
}
static __device__ __forceinline__ float b2f_s(short s){
  return __uint_as_float(((unsigned int)(unsigned short)s) << 16);
}
static __device__ __forceinline__ short8 ld_frag_f32(const float* p){
  float4 f0 = *(const float4*)p;
  float4 f1 = *(const float4*)(p + 4);
  short8 v;
  v[0]=bf16b(f0.x); v[1]=bf16b(f0.y); v[2]=bf16b(f0.z); v[3]=bf16b(f0.w);
  v[4]=bf16b(f1.x); v[5]=bf16b(f1.y); v[6]=bf16b(f1.z); v[7]=bf16b(f1.w);
  return v;
}

// ---- rel transfer, optionally fused with the PREVIOUS layer's trailing LN.
template<bool PRE_LN>
__global__ void __launch_bounds__(256) k_rel_transfer(float* __restrict__ rel,
    const float* __restrict__ rtw, const float* __restrict__ rtb,
    const float* __restrict__ g, const float* __restrict__ b,
    const float* __restrict__ gp, const float* __restrict__ bp, int rows){
  __shared__ float xrow[4][DD];
  float* xl = xrow[threadIdx.x >> 6];
  const int lane = threadIdx.x & 63;
  int wave = (int)((blockIdx.x * blockDim.x + threadIdx.x) >> 6);
  if (wave >= rows) return;
  int row = __builtin_amdgcn_readfirstlane(wave);
  float* x = rel + (size_t)row * DD;
  float t0 = x[lane], t1 = x[64 + lane];
  if (PRE_LN){
    float mu = wave_sum(t0 + t1) * (1.0f/128.0f);
    float e0 = t0 - mu, e1 = t1 - mu;
    float var = wave_sum(e0*e0 + e1*e1) * (1.0f/128.0f);
    float rs = rsqrtf(var + LNEPS);
    t0 = e0 * rs * gp[lane]      + bp[lane];
    t1 = e1 * rs * gp[64 + lane] + bp[64 + lane];
  }
  xl[lane] = t0; xl[64 + lane] = t1;
  float y0 = 0.f, y1 = 0.f;
#pragma unroll 4
  for (int d = 0; d < DD; ++d){
    float xd = xl[d];
    y0 = fmaf(xd, rtw[d*DD + lane],      y0);
    y1 = fmaf(xd, rtw[d*DD + 64 + lane], y1);
  }
  float u0 = t0 + fmaxf(y0 + rtb[lane],      0.f);
  float u1 = t1 + fmaxf(y1 + rtb[64 + lane], 0.f);
  float mu = wave_sum(u0 + u1) * (1.0f/128.0f);
  float e0 = u0 - mu, e1 = u1 - mu;
  float var = wave_sum(e0*e0 + e1*e1) * (1.0f/128.0f);
  float rs = rsqrtf(var + LNEPS);
  x[lane]      = e0 * rs * g[lane]      + b[lane];
  x[64 + lane] = e1 * rs * g[64 + lane] + b[64 + lane];
}

// ---- prep bf16 B-fragments from k-major weight W[K=128][C] (ldc = C)
__global__ void __launch_bounds__(256) k_prep_bfrag_km(const float* __restrict__ W,
    short* __restrict__ out, int C, int ldc){
  int idx = blockIdx.x * blockDim.x + threadIdx.x;
  int total = (C >> 4) * 4 * 64;
  if (idx >= total) return;
  int lane = idx & 63, ks = (idx >> 6) & 3, ct = idx >> 8;
  int k = ks*32 + ((lane >> 4) << 3);
  int c = (ct << 4) + (lane & 15);
  short8 v;
#pragma unroll
  for (int j = 0; j < 8; ++j) v[j] = bf16b(W[(size_t)(k + j)*ldc + c]);
  *reinterpret_cast<short8*>(out + (size_t)idx * 8) = v;
}

// ---- prep bf16 B-fragments from c-major weight W[Nc][128] (PyTorch [out,in])
__global__ void __launch_bounds__(256) k_prep_bfrag(const float* __restrict__ W,
    short* __restrict__ out, int Nc){
  int idx = blockIdx.x * blockDim.x + threadIdx.x;
  int total = (Nc >> 4) * 4 * 64;
  if (idx >= total) return;
  int lane = idx & 63, ks = (idx >> 6) & 3, ct = idx >> 8;
  int k = ks*32 + ((lane >> 4) << 3);
  int c = (ct << 4) + (lane & 15);
  const float* src = W + (size_t)c * DD + k;
  short8 v;
#pragma unroll
  for (int j = 0; j < 8; ++j) v[j] = bf16b(src[j]);
  *reinterpret_cast<short8*>(out + (size_t)idx * 8) = v;
}

// ---- MFMA projection + fused bf16 gather-table build (layer-0 N + rel tables)
__global__ void __launch_bounds__(256) k_proj_gt(const float* __restrict__ X,
    const short* __restrict__ Bf, unsigned short* __restrict__ GT, int rows){
  const int lane = threadIdx.x & 63;
  int wave = (int)((blockIdx.x * blockDim.x + threadIdx.x) >> 6);
  int r0 = wave * 16;
  if (r0 >= rows) return;
  if (r0 + 16 > rows) r0 = rows - 16;
  r0 = __builtin_amdgcn_readfirstlane(r0);
  const int arow = lane & 15;
  const int koff = (lane >> 4) << 3;
  short8 ax[4];
#pragma unroll
  for (int ks = 0; ks < 4; ++ks){
    ax[ks] = ld_frag_f32(X + (size_t)(r0 + arow) * DD + ks*32 + koff);
    *reinterpret_cast<short8*>((short*)GT + (size_t)(r0 + arow) * GTS + 64 + ks*32 + koff) = ax[ks];
  }
  f32x4 acc[4];
#pragma unroll
  for (int ct = 0; ct < 4; ++ct){
    acc[ct] = (f32x4)0.f;
#pragma unroll
    for (int ks = 0; ks < 4; ++ks){
      short8 bw = *reinterpret_cast<const short8*>(Bf + ((size_t)(ct*4 + ks)*64 + lane)*8);
      acc[ct] = __builtin_amdgcn_mfma_f32_16x16x32_bf16(ax[ks], bw, acc[ct], 0, 0, 0);
    }
  }
#pragma unroll
  for (int ct = 0; ct < 4; ++ct){
    int col = ct*16 + (lane & 15);
#pragma unroll
    for (int reg = 0; reg < 4; ++reg){
      int row = r0 + ((lane >> 4) << 2) + reg;
      ((short*)GT)[(size_t)row*GTS + col] = bf16b(acc[ct][reg]);
    }
  }
}

// ---- qr[b,:] = rel[q_rel[b]+b*Rp1,:] @ Wqr + bias
__global__ void __launch_bounds__(256) k_projq(const float* __restrict__ rel,
    const float* __restrict__ Wqr, const float* __restrict__ bias,
    const int* __restrict__ q_rel, float* __restrict__ out, int Bc, int Rp1){
  const int lane = threadIdx.x & 63;
  int wave = (int)((blockIdx.x * blockDim.x + threadIdx.x) >> 6);
  if (wave >= Bc) return;
  int b = __builtin_amdgcn_readfirstlane(wave);
  int f = __builtin_amdgcn_readfirstlane(q_rel[b] + b * Rp1);
  const float* x = rel + (size_t)f * DD;
  float a = 0.f;
#pragma unroll 4
  for (int d = 0; d < DD; ++d) a = fmaf(x[d], Wqr[d*AA + lane], a);
  out[(size_t)b*AA + lane] = a + bias[lane];
}

// ================= CSR build (once per call; obj constant across layers) ====
__global__ void __launch_bounds__(256) k_hist(const int* __restrict__ obj, int* __restrict__ deg, int E){
  int idx = blockIdx.x * blockDim.x + threadIdx.x;
  if (idx < E) atomicAdd(&deg[obj[idx]], 1);
}

__global__ void __launch_bounds__(1024) k_scan1(const int* __restrict__ deg,
    int* __restrict__ row_start, int* __restrict__ bsum, int n){
  __shared__ int sm[1024];
  int t = threadIdx.x;
  int i = blockIdx.x * 1024 + t;
  int v = (i < n) ? deg[i] : 0;
  sm[t] = v; __syncthreads();
#pragma unroll
  for (int off = 1; off < 1024; off <<= 1){
    int x = (t >= off) ? sm[t - off] : 0;
    __syncthreads();
    sm[t] += x;
    __syncthreads();
  }
  if (i < n) row_start[i] = sm[t] - v;
  if (t == 1023) bsum[blockIdx.x] = sm[1023];
}

__global__ void __launch_bounds__(1024) k_scan2(int* __restrict__ bsum, int nb){
  __shared__ int sm[1024];
  int t = threadIdx.x;
  int v = (t < nb) ? bsum[t] : 0;
  sm[t] = v; __syncthreads();
#pragma unroll
  for (int off = 1; off < 1024; off <<= 1){
    int x = (t >= off) ? sm[t - off] : 0;
    __syncthreads();
    sm[t] += x;
    __syncthreads();
  }
  if (t < nb) bsum[t] = sm[t] - v;
}

__global__ void __launch_bounds__(256) k_scan3(int* __restrict__ row_start,
    const int* __restrict__ bsum, int n, int E){
  int i = blockIdx.x * blockDim.x + threadIdx.x;
  if (i < n) row_start[i] += bsum[i >> 10];
  if (i == 0) row_start[n] = E;
}

// ---- scatter PACKED edge records into CSR order: rec = s | f<<17 | b<<28
__global__ void __launch_bounds__(256) k_scatter_edges(const int* __restrict__ obj,
    const int* __restrict__ sub, const int* __restrict__ bidx,
    const int* __restrict__ reli, const int* __restrict__ row_start,
    int* __restrict__ cursor, unsigned int* __restrict__ ER, int E, int Rp1){
  int e = blockIdx.x * blockDim.x + threadIdx.x;
  if (e < E){
    int o = obj[e];
    int pos = row_start[o] + atomicAdd(&cursor[o], 1);
    int bb = bidx[e];
    unsigned rec = (unsigned)sub[e] | ((unsigned)(reli[e] + bb * Rp1) << 17)
                 | ((unsigned)bb << 28);
    ER[pos] = rec;
  }
}

// ---- CSR edge kernel over packed records (round-9 version, unchanged)
__global__ void __launch_bounds__(256) k_edge_csr4(
    const unsigned short* __restrict__ GT, const unsigned short* __restrict__ RT,
    const float* __restrict__ qr,
    const float* __restrict__ wal, const float* __restrict__ walb_p,
    const unsigned int* __restrict__ ER, const int* __restrict__ row_start,
    float* __restrict__ agg, int Nn){
  const int lane = threadIdx.x & 63;
  const int g = lane >> 4;
  const int t = lane & 15;
  int wave = (int)((blockIdx.x * blockDim.x + threadIdx.x) >> 6);
  if (wave >= Nn) return;
  int o = __builtin_amdgcn_readfirstlane(wave);
  const int s0 = __builtin_amdgcn_readfirstlane(row_start[o]);
  const int s1 = __builtin_amdgcn_readfirstlane(row_start[o + 1]);
  const float4 wa4 = *reinterpret_cast<const float4*>(wal + t*4);
  const float wb = walb_p[0];
  float acc[8];
#pragma unroll
  for (int i = 0; i < 8; ++i) acc[i] = 0.f;
  for (int base = s0; base < s1; base += 8){
    int pA = base + g;
    int pB = base + g + 4;
    bool vA = pA < s1, vB = pB < s1;
    unsigned eA = ER[vA ? pA : s0];
    unsigned eB = ER[vB ? pB : s0];
    int sA = eA & 0x1FFFF, fA = (eA >> 17) & 0x7FF, bA = eA >> 28;
    int sB = eB & 0x1FFFF, fB = (eB >> 17) & 0x7FF, bB = eB >> 28;
    const unsigned short* gsA = GT + (size_t)sA * GTS;
    const unsigned short* rfA = RT + (size_t)fA * GTS;
    const unsigned short* gsB = GT + (size_t)sB * GTS;
    const unsigned short* rfB = RT + (size_t)fB * GTS;
    uint2 pgA = *reinterpret_cast<const uint2*>(gsA + t*4);
    uint2 prA = *reinterpret_cast<const uint2*>(rfA + t*4);
    float4 q4A = *reinterpret_cast<const float4*>(qr + (size_t)bA*AA + t*4);
    uint4 xgA = *reinterpret_cast<const uint4*>(gsA + 64 + t*8);
    uint4 xrA = *reinterpret_cast<const uint4*>(rfA + 64 + t*8);
    uint2 pgB = *reinterpret_cast<const uint2*>(gsB + t*4);
    uint2 prB = *reinterpret_cast<const uint2*>(rfB + t*4);
    float4 q4B = *reinterpret_cast<const float4*>(qr + (size_t)bB*AA + t*4);
    uint4 xgB = *reinterpret_cast<const uint4*>(gsB + 64 + t*8);
    uint4 xrB = *reinterpret_cast<const uint4*>(rfB + 64 + t*8);
    float pA0 = b2f_lo(pgA.x) + b2f_lo(prA.x) + q4A.x;
    float pA1 = b2f_hi(pgA.x) + b2f_hi(prA.x) + q4A.y;
    float pA2 = b2f_lo(pgA.y) + b2f_lo(prA.y) + q4A.z;
    float pA3 = b2f_hi(pgA.y) + b2f_hi(prA.y) + q4A.w;
    float dotA = rrelu_f(pA0)*wa4.x + rrelu_f(pA1)*wa4.y
               + rrelu_f(pA2)*wa4.z + rrelu_f(pA3)*wa4.w;
    float pB0 = b2f_lo(pgB.x) + b2f_lo(prB.x) + q4B.x;
    float pB1 = b2f_hi(pgB.x) + b2f_hi(prB.x) + q4B.y;
    float pB2 = b2f_lo(pgB.y) + b2f_lo(prB.y) + q4B.z;
    float pB3 = b2f_hi(pgB.y) + b2f_hi(prB.y) + q4B.w;
    float dotB = rrelu_f(pB0)*wa4.x + rrelu_f(pB1)*wa4.y
               + rrelu_f(pB2)*wa4.z + rrelu_f(pB3)*wa4.w;
#pragma unroll
    for (int off = 1; off < 16; off <<= 1){
      dotA += __shfl_xor(dotA, off, 64);
      dotB += __shfl_xor(dotB, off, 64);
    }
    float alA = vA ? sigm(dotA + wb) : 0.f;
    float alB = vB ? sigm(dotB + wb) : 0.f;
    acc[0] = fmaf(alA, b2f_lo(xgA.x) + b2f_lo(xrA.x), fmaf(alB, b2f_lo(xgB.x) + b2f_lo(xrB.x), acc[0]));
    acc[1] = fmaf(alA, b2f_hi(xgA.x) + b2f_hi(xrA.x), fmaf(alB, b2f_hi(xgB.x) + b2f_hi(xrB.x), acc[1]));
    acc[2] = fmaf(alA, b2f_lo(xgA.y) + b2f_lo(xrA.y), fmaf(alB, b2f_lo(xgB.y) + b2f_lo(xrB.y), acc[2]));
    acc[3] = fmaf(alA, b2f_hi(xgA.y) + b2f_hi(xrA.y), fmaf(alB, b2f_hi(xgB.y) + b2f_hi(xrB.y), acc[3]));
    acc[4] = fmaf(alA, b2f_lo(xgA.z) + b2f_lo(xrA.z), fmaf(alB, b2f_lo(xgB.z) + b2f_lo(xrB.z), acc[4]));
    acc[5] = fmaf(alA, b2f_hi(xgA.z) + b2f_hi(xrA.z), fmaf(alB, b2f_hi(xgB.z) + b2f_hi(xrB.z), acc[5]));
    acc[6] = fmaf(alA, b2f_lo(xgA.w) + b2f_lo(xrA.w), fmaf(alB, b2f_lo(xgB.w) + b2f_lo(xrB.w), acc[6]));
    acc[7] = fmaf(alA, b2f_hi(xgA.w) + b2f_hi(xrA.w), fmaf(alB, b2f_hi(xgB.w) + b2f_hi(xrB.w), acc[7]));
  }
#pragma unroll
  for (int i = 0; i < 8; ++i){
    acc[i] += __shfl_xor(acc[i], 16, 64);
    acc[i] += __shfl_xor(acc[i], 32, 64);
  }
  if (g == 0){
    float4 v0 = make_float4(acc[0], acc[1], acc[2], acc[3]);
    float4 v1 = make_float4(acc[4], acc[5], acc[6], acc[7]);
    *reinterpret_cast<float4*>(agg + (size_t)o*DD + t*8)     = v0;
    *reinterpret_cast<float4*>(agg + (size_t)o*DD + t*8 + 4) = v1;
  }
}

// ---- FUSED: H = gru(x = LN(rrelu(AGG@Wh)), h = H), in place.
// Round-10 staging (16 units x 12 frags, double-buffered, LDS 42KB -> 3 blk/CU)
// + round-11 epilogue fusion (PROJ: next-layer GT; SCORE: final score+winner).
// hv buffered in registers (reuse acc[]); LDS H-tile written once in epilogue.
template<bool HAS_H, bool PROJ, bool SCORE>
__global__ void __launch_bounds__(256) k_whlngru(const float* __restrict__ AGG,
    float* H, const short* __restrict__ Bwh, const short* __restrict__ Bih,
    const short* __restrict__ Bhh, const float* __restrict__ lng,
    const float* __restrict__ lnb, const float* __restrict__ bih,
    const float* __restrict__ bhh,
    const short* __restrict__ Bproj, unsigned short* __restrict__ GT,
    const float* __restrict__ wf, const int* __restrict__ nbp,
    const int* __restrict__ nep, float* __restrict__ scores,
    int* __restrict__ winner, int NENT, int rows){
  constexpr int NU = HAS_H ? 16 : 8;        // staging units: (ct, ih/hh)
  __shared__ short xtile[4 * 16 * XPAD];
  __shared__ short wbuf[2][12 * 512];
  short* xl = xtile + (threadIdx.x >> 6) * 16 * XPAD;
  const int lane = threadIdx.x & 63;
  const int wib  = threadIdx.x >> 6;
  int wave = (int)((blockIdx.x * blockDim.x + threadIdx.x) >> 6);
  const bool live = (wave * 16 < rows);
  int r0 = live ? wave * 16 : 0;
  if (r0 + 16 > rows) r0 = rows - 16;
  r0 = __builtin_amdgcn_readfirstlane(r0);
  const int arow = lane & 15;
  const int koff = (lane >> 4) << 3;
  const int lrbase = (lane >> 4) << 2;

  // cooperative stage of unit u into wbuf[par]: 12 frags, 3 per wave
  auto stage = [&](int u, int par){
    int ct = HAS_H ? (u >> 1) : u;
    const short* src = (HAS_H && (u & 1)) ? Bhh : Bih;
#pragma unroll
    for (int jj = 0; jj < 3; ++jj){
      int j = wib * 3 + jj;                       // 0..11 = gate*4+ks
      int gfrag = (j >> 2) * 32 + ct * 4 + (j & 3);
      *reinterpret_cast<short8*>(&wbuf[par][j * 512 + lane * 8]) =
          *reinterpret_cast<const short8*>(src + (size_t)gfrag * 512 + lane * 8);
    }
  };

  stage(0, 0);   // overlap unit-0 staging with phase 1

  // ---- phase 1: acc[ct] = (AGG @ Wh) tile, rrelu (Bwh from global)
  short8 aa[4];
#pragma unroll
  for (int ks = 0; ks < 4; ++ks)
    aa[ks] = ld_frag_f32(AGG + (size_t)(r0 + arow) * DD + ks*32 + koff);
  f32x4 acc[8];
#pragma unroll
  for (int ct = 0; ct < 8; ++ct){
    acc[ct] = (f32x4)0.f;
#pragma unroll
    for (int ks = 0; ks < 4; ++ks){
      short8 bw = *reinterpret_cast<const short8*>(Bwh + ((size_t)(ct*4 + ks)*64 + lane)*8);
      acc[ct] = __builtin_amdgcn_mfma_f32_16x16x32_bf16(aa[ks], bw, acc[ct], 0, 0, 0);
    }
  }
#pragma unroll
  for (int ct = 0; ct < 8; ++ct)
#pragma unroll
    for (int reg = 0; reg < 4; ++reg) acc[ct][reg] = rrelu_f(acc[ct][reg]);

  // ---- in-wave LayerNorm per row, write bf16 X-tile to per-wave LDS
  float mu[4], rs[4];
#pragma unroll
  for (int reg = 0; reg < 4; ++reg){
    float s = 0.f, ss = 0.f;
#pragma unroll
    for (int ct = 0; ct < 8; ++ct){ float v = acc[ct][reg]; s += v; ss += v*v; }
    s = red16(s); ss = red16(ss);
    float m = s * (1.0f/128.0f);
    float var = ss * (1.0f/128.0f) - m*m;
    mu[reg] = m;
    rs[reg] = rsqrtf(var + LNEPS);
  }
#pragma unroll
  for (int ct = 0; ct < 8; ++ct){
    int col = ct*16 + (lane & 15);
    float gv = lng[col], bv = lnb[col];
#pragma unroll
    for (int reg = 0; reg < 4; ++reg){
      float xn = (acc[ct][reg] - mu[reg]) * rs[reg] * gv + bv;
      xl[(lrbase + reg) * XPAD + col] = bf16b(xn);
    }
  }

  // ---- A-fragments for phase 2
  short8 ax[4], ah8[4];
#pragma unroll
  for (int ks = 0; ks < 4; ++ks)
    ax[ks] = *reinterpret_cast<const short8*>(&xl[arow * XPAD + ks*32 + koff]);
  if (HAS_H){
#pragma unroll
    for (int ks = 0; ks < 4; ++ks)
      ah8[ks] = ld_frag_f32(H + (size_t)(r0 + arow) * DD + ks*32 + koff);
  }

  __syncthreads();   // wbuf[0] (unit 0) ready

  // ---- phase 2: GRU; gate weights from double-buffered staged LDS.
  // hv results buffered into acc[ct] (dead after LN) for the epilogue.
  f32x4 air = (f32x4)0.f, aiz = (f32x4)0.f, ain = (f32x4)0.f;
  f32x4 ahr = (f32x4)0.f, ahz = (f32x4)0.f, ahn = (f32x4)0.f;
#pragma unroll
  for (int u = 0; u < NU; ++u){
    if (u + 1 < NU) stage(u + 1, (u + 1) & 1);
    const short* wb = wbuf[u & 1];
    const bool is_hh = HAS_H && (u & 1);
    const int ct = HAS_H ? (u >> 1) : u;
    if (!is_hh){
      air = (f32x4)0.f; aiz = (f32x4)0.f; ain = (f32x4)0.f;
      ahr = (f32x4)0.f; ahz = (f32x4)0.f; ahn = (f32x4)0.f;
    }
#pragma unroll
    for (int ks = 0; ks < 4; ++ks){
      short8 b0 = *reinterpret_cast<const short8*>(&wb[(0*4 + ks)*512 + lane*8]);
      short8 b1 = *reinterpret_cast<const short8*>(&wb[(1*4 + ks)*512 + lane*8]);
      short8 b2 = *reinterpret_cast<const short8*>(&wb[(2*4 + ks)*512 + lane*8]);
      if (!is_hh){
        air = __builtin_amdgcn_mfma_f32_16x16x32_bf16(ax[ks], b0, air, 0, 0, 0);
        aiz = __builtin_amdgcn_mfma_f32_16x16x32_bf16(ax[ks], b1, aiz, 0, 0, 0);
        ain = __builtin_amdgcn_mfma_f32_16x16x32_bf16(ax[ks], b2, ain, 0, 0, 0);
      } else {
        ahr = __builtin_amdgcn_mfma_f32_16x16x32_bf16(ah8[ks], b0, ahr, 0, 0, 0);
        ahz = __builtin_amdgcn_mfma_f32_16x16x32_bf16(ah8[ks], b1, ahz, 0, 0, 0);
        ahn = __builtin_amdgcn_mfma_f32_16x16x32_bf16(ah8[ks], b2, ahn, 0, 0, 0);
      }
    }
    if (!HAS_H || is_hh){
      int col = ct*16 + (lane & 15);
      float bi_r = bih[col], bi_z = bih[128 + col], bi_n = bih[256 + col];
      float bh_r = bhh[col], bh_z = bhh[128 + col], bh_n = bhh[256 + col];
#pragma unroll
      for (int reg = 0; reg < 4; ++reg){
        int row = r0 + lrbase + reg;
        float gi_r = air[reg] + bi_r;
        float gi_z = aiz[reg] + bi_z;
        float gi_n = ain[reg] + bi_n;
        float gh_r = (HAS_H ? ahr[reg] : 0.f) + bh_r;
        float gh_z = (HAS_H ? ahz[reg] : 0.f) + bh_z;
        float gh_n = (HAS_H ? ahn[reg] : 0.f) + bh_n;
        float rg = sigm(gi_r + gh_r);
        float zg = sigm(gi_z + gh_z);
        float ng = fast_tanh(gi_n + rg * gh_n);
        float hp = HAS_H ? H[(size_t)row * DD + col] : 0.f;
        float hv = (1.f - zg) * ng + zg * hp;
        if (!SCORE && live) H[(size_t)row * DD + col] = hv;
        acc[ct][reg] = hv;
      }
    }
    __syncthreads();
  }

  // ---- epilogue: fused next-layer projection / final score from H-tile (in acc)
  if (PROJ || SCORE){
    // write H-tile to per-wave LDS (wave-local: no barrier needed before reads)
#pragma unroll
    for (int ct = 0; ct < 8; ++ct){
      int col = ct*16 + (lane & 15);
#pragma unroll
      for (int reg = 0; reg < 4; ++reg)
        xl[(lrbase + reg) * XPAD + col] = bf16b(acc[ct][reg]);
    }
    short8 hx[4];
#pragma unroll
    for (int ks = 0; ks < 4; ++ks)
      hx[ks] = *reinterpret_cast<const short8*>(&xl[arow * XPAD + ks*32 + koff]);
    if (PROJ){
      if (live){
#pragma unroll
        for (int ks = 0; ks < 4; ++ks)
          *reinterpret_cast<short8*>((short*)GT + (size_t)(r0 + arow) * GTS + 64 + ks*32 + koff) = hx[ks];
      }
      f32x4 pacc[4];
#pragma unroll
      for (int ct = 0; ct < 4; ++ct){
        pacc[ct] = (f32x4)0.f;
#pragma unroll
        for (int ks = 0; ks < 4; ++ks){
          short8 bw = *reinterpret_cast<const short8*>(Bproj + ((size_t)(ct*4 + ks)*64 + lane)*8);
          pacc[ct] = __builtin_amdgcn_mfma_f32_16x16x32_bf16(hx[ks], bw, pacc[ct], 0, 0, 0);
        }
      }
      if (live){
#pragma unroll
        for (int ct = 0; ct < 4; ++ct){
          int col = ct*16 + (lane & 15);
#pragma unroll
          for (int reg = 0; reg < 4; ++reg){
            int row = r0 + lrbase + reg;
            ((short*)GT)[(size_t)row*GTS + col] = bf16b(pacc[ct][reg]);
          }
        }
      }
    }
    if (SCORE){
      float part = 0.f;
#pragma unroll
      for (int ks = 0; ks < 4; ++ks){
#pragma unroll
        for (int j = 0; j < 8; ++j)
          part = fmaf(b2f_s(hx[ks][j]), wf[ks*32 + koff + j], part);
      }
      part += __shfl_xor(part, 16, 64);
      part += __shfl_xor(part, 32, 64);
      if (live && (lane >> 4) == 0){
        int row = r0 + arow;
        scores[row] = part;
        int slot = nbp[row] * NENT + nep[row];
        atomicMax(&winner[slot], row);
      }
    }
  }
}

__global__ void __launch_bounds__(256) k_scatter(const float* __restrict__ scores,
    const int* __restrict__ winner, const int* __restrict__ nb, const int* __restrict__ ne,
    float* __restrict__ out, int rows, int NENT){
  int n = blockIdx.x * blockDim.x + threadIdx.x;
  if (n < rows){
    int slot = nb[n] * NENT + ne[n];
    if (winner[slot] == n) out[slot] = scores[n];
  }
}

extern "C" void kernel_launch(void* const* d_in, const int* in_sizes, int n_in,
                              void* d_out, int out_size, void* d_ws, size_t ws_size,
                              hipStream_t stream){
  const float* hidden0 = (const float*)d_in[0];
  const float* rel0    = (const float*)d_in[1];
  const int* batch_idx = (const int*)d_in[2];
  const int* rel_i     = (const int*)d_in[3];
  const int* sub       = (const int*)d_in[4];
  const int* obj       = (const int*)d_in[5];
  const int* q_rel     = (const int*)d_in[6];
  const int* nb        = (const int*)d_in[7];
  const int* ne        = (const int*)d_in[8];
  const float* Ws      = (const float*)d_in[9];
  const float* Wr      = (const float*)d_in[10];
  const float* Wqr_w   = (const float*)d_in[11];
  const float* Wqr_b   = (const float*)d_in[12];
  const float* Wal_w   = (const float*)d_in[13];
  const float* Wal_b   = (const float*)d_in[14];
  const float* Wh      = (const float*)d_in[15];
  const float* rt_w    = (const float*)d_in[16];
  const float* rt_b    = (const float*)d_in[17];
  const float* ln_g    = (const float*)d_in[18];
  const float* ln_b    = (const float*)d_in[19];
  const float* lnr_g   = (const float*)d_in[20];
  const float* lnr_b   = (const float*)d_in[21];
  const float* wih     = (const float*)d_in[22];
  const float* whh     = (const float*)d_in[23];
  const float* bih     = (const float*)d_in[24];
  const float* bhh     = (const float*)d_in[25];
  const float* wfin    = (const float*)d_in[26];

  const int N    = in_sizes[0] / DD;
  const int NR   = in_sizes[1] / DD;
  const int E    = in_sizes[2];
  const int Bc   = in_sizes[6];
  const int L    = in_sizes[14];
  const int Rp1  = NR / Bc;
  const int NENT = out_size / Bc;

  char* wsp = (char*)d_ws;
  auto alloc = [&](size_t bytes) -> void* {
    void* p = (void*)wsp;
    wsp += (bytes + 255) & ~(size_t)255;
    return p;
  };
  float* AGG     = (float*)alloc((size_t)N * DD * 4);
  float* HBUF    = (float*)alloc((size_t)N * DD * 4);
  float* rel_cur = (float*)alloc((size_t)NR * DD * 4);
  unsigned short* GT = (unsigned short*)alloc((size_t)N * GTS * 2);
  unsigned short* RT = (unsigned short*)alloc((size_t)NR * GTS * 2);
  float* qr      = (float*)alloc((size_t)Bc * AA * 4);
  short* Bih     = (short*)alloc((size_t)(GG/16) * 4 * 64 * 8 * 2);
  short* Bhh     = (short*)alloc((size_t)(GG/16) * 4 * 64 * 8 * 2);
  short* Bws     = (short*)alloc((size_t)L * 4 * 4 * 64 * 8 * 2);
  short* Bwr     = (short*)alloc((size_t)L * 4 * 4 * 64 * 8 * 2);
  short* Bwh     = (short*)alloc((size_t)L * 8 * 4 * 64 * 8 * 2);
  float* scores  = (float*)alloc((size_t)N * 4);
  int*   winner  = (int*)alloc((size_t)Bc * NENT * 4);
  int*   deg     = (int*)alloc((size_t)N * 4);
  int*   row_st  = (int*)alloc((size_t)(N + 1) * 4);
  int*   cursor  = (int*)alloc((size_t)N * 4);
  unsigned int* ER = (unsigned int*)alloc((size_t)E * 4);
  int*   bsum    = (int*)alloc((size_t)1024 * 4);
  (void)ws_size; (void)n_in;

  hipMemcpyAsync(rel_cur, rel0, (size_t)NR * DD * 4, hipMemcpyDeviceToDevice, stream);
  {
    int totg = (GG/16) * 4 * 64;
    k_prep_bfrag<<<(totg + 255)/256, 256, 0, stream>>>(wih, Bih, GG);
    k_prep_bfrag<<<(totg + 255)/256, 256, 0, stream>>>(whh, Bhh, GG);
    int tot64 = 4 * 4 * 64;          // C=64 fragments
    int tot128 = 8 * 4 * 64;         // C=128 fragments
    for (int i = 0; i < L; ++i){
      k_prep_bfrag_km<<<(tot64 + 255)/256, 256, 0, stream>>>(Ws + (size_t)i*DD*AA, Bws + (size_t)i*tot64*8, AA, AA);
      k_prep_bfrag_km<<<(tot64 + 255)/256, 256, 0, stream>>>(Wr + (size_t)i*DD*AA, Bwr + (size_t)i*tot64*8, AA, AA);
      k_prep_bfrag_km<<<(tot128 + 255)/256, 256, 0, stream>>>(Wh + (size_t)i*DD*DD, Bwh + (size_t)i*tot128*8, DD, DD);
    }
  }
  hipMemsetAsync(d_out, 0, (size_t)out_size * 4, stream);
  hipMemsetAsync(winner, 0xFF, (size_t)Bc * NENT * 4, stream);

  // ---- build CSR over obj with packed edge records (constant across layers)
  hipMemsetAsync(deg, 0, (size_t)N * 4, stream);
  hipMemsetAsync(cursor, 0, (size_t)N * 4, stream);
  k_hist<<<(E + 255)/256, 256, 0, stream>>>(obj, deg, E);
  {
    int nb1 = (N + 1023)/1024;
    k_scan1<<<nb1, 1024, 0, stream>>>(deg, row_st, bsum, N);
    k_scan2<<<1, 1024, 0, stream>>>(bsum, nb1);
    k_scan3<<<(N + 255)/256, 256, 0, stream>>>(row_st, bsum, N, E);
  }
  k_scatter_edges<<<(E + 255)/256, 256, 0, stream>>>(obj, sub, batch_idx, rel_i,
      row_st, cursor, ER, E, Rp1);

  auto blocks4 = [](int waves){ return (waves + 3) / 4; };
  const int tot64 = 4 * 4 * 64;
  const int tot128 = 8 * 4 * 64;

  for (int i = 0; i < L; ++i){
    if (i == 0)
      k_rel_transfer<false><<<blocks4(NR), 256, 0, stream>>>(rel_cur,
          rt_w + (size_t)i*DD*DD, rt_b + (size_t)i*DD,
          lnr_g + (size_t)i*DD, lnr_b + (size_t)i*DD,
          nullptr, nullptr, NR);
    else
      k_rel_transfer<true><<<blocks4(NR), 256, 0, stream>>>(rel_cur,
          rt_w + (size_t)i*DD*DD, rt_b + (size_t)i*DD,
          lnr_g + (size_t)i*DD, lnr_b + (size_t)i*DD,
          lnr_g + (size_t)(i-1)*DD, lnr_b + (size_t)(i-1)*DD, NR);
    if (i == 0)   // later layers: GT is produced by the previous whlngru (PROJ)
      k_proj_gt<<<blocks4((N+15)/16), 256, 0, stream>>>(hidden0, Bws, GT, N);
    k_proj_gt<<<blocks4((NR+15)/16), 256, 0, stream>>>(rel_cur, Bwr + (size_t)i*tot64*8, RT, NR);
    k_projq<<<blocks4(Bc), 256, 0, stream>>>(rel_cur, Wqr_w + (size_t)i*DD*AA,
        Wqr_b + (size_t)i*AA, q_rel, qr, Bc, Rp1);
    k_edge_csr4<<<blocks4(N), 256, 0, stream>>>(GT, RT, qr,
        Wal_w + (size_t)i*AA, Wal_b + i, ER, row_st, AGG, N);
    {
      int waves = (N + 15)/16;
      int blocks = blocks4(waves);
      const bool has_h = (i > 0);
      const bool proj  = (i + 1 < L);
      const bool score = (i == L - 1);
      const short* Bp = proj ? (Bws + (size_t)(i+1)*tot64*8) : nullptr;
      const float* lg = ln_g + (size_t)i*DD;
      const float* lb = ln_b + (size_t)i*DD;
      const short* Bw = Bwh + (size_t)i*tot128*8;
      if (!has_h && proj && !score)
        k_whlngru<false,true,false><<<blocks, 256, 0, stream>>>(AGG, HBUF, Bw, Bih, Bhh,
            lg, lb, bih, bhh, Bp, GT, wfin, nb, ne, scores, winner, NENT, N);
      else if (!has_h && !proj && score)
        k_whlngru<false,false,true><<<blocks, 256, 0, stream>>>(AGG, HBUF, Bw, Bih, Bhh,
            lg, lb, bih, bhh, Bp, GT, wfin, nb, ne, scores, winner, NENT, N);
      else if (has_h && proj && !score)
        k_whlngru<true,true,false><<<blocks, 256, 0, stream>>>(AGG, HBUF, Bw, Bih, Bhh,
            lg, lb, bih, bhh, Bp, GT, wfin, nb, ne, scores, winner, NENT, N);
      else
        k_whlngru<true,false,true><<<blocks, 256, 0, stream>>>(AGG, HBUF, Bw, Bih, Bhh,
            lg, lb, bih, bhh, Bp, GT, wfin, nb, ne, scores, winner, NENT, N);
    }
  }

  k_scatter<<<(N + 255)/256, 256, 0, stream>>>(scores, winner, nb, ne, (float*)d_out, N, NENT);
}

// Round 13
// 453.338 us; speedup vs baseline: 1.0634x; 1.0634x over previous
//
#include <hip/hip_runtime.h>
#include <hip/hip_bf16.h>

constexpr int DD = 128;   // hidden dim D
constexpr int AA = 64;    // attention dim A
constexpr int GG = 384;   // 3*D (GRU gates)
constexpr int XPAD = 136; // LDS X-tile row stride in shorts (128 + 8 pad)
constexpr int GTS = 192;  // gather-table row stride in shorts: 64 proj + 128 x

#define SLOPE_F 0.22916666666666666f
#define LNEPS   1e-5f

typedef __attribute__((ext_vector_type(8))) short short8;
typedef __attribute__((ext_vector_type(4))) float f32x4;

static __device__ __forceinline__ float wave_sum(float v){
#pragma unroll
  for (int off = 32; off > 0; off >>= 1) v += __shfl_xor(v, off, 64);
  return v;
}
static __device__ __forceinline__ float red16(float v){
#pragma unroll
  for (int off = 1; off < 16; off <<= 1) v += __shfl_xor(v, off, 64);
  return v;
}
static __device__ __forceinline__ float sigm(float x){ return 1.0f / (1.0f + __expf(-x)); }
static __device__ __forceinline__ float fast_tanh(float x){
  float ax = fabsf(x);
  float t = __expf(-2.0f * ax);
  float r = (1.0f - t) / (1.0f + t);
  return copysignf(r, x);
}
static __device__ __forceinline__ float rrelu_f(float x){ return x >= 0.0f ? x : SLOPE_F * x; }
static __device__ __forceinline__ short bf16b(float f){
  __hip_bfloat16 h = __float2bfloat16(f);
  return *reinterpret_cast<short*>(&h);
}
static __device__ __forceinline__ float b2f_lo(unsigned int x){
  return __uint_as_float(x << 16);
}
static __device__ __forceinline__ float b2f_hi(unsigned int x){
  return __uint_as_float(x & 0xffff0000u);
}
static __device__ __forceinline__ float b2f_s(short s){
  return __uint_as_float(((unsigned int)(unsigned short)s) << 16);
}
static __device__ __forceinline__ short8 ld_frag_f32(const float* p){
  float4 f0 = *(const float4*)p;
  float4 f1 = *(const float4*)(p + 4);
  short8 v;
  v[0]=bf16b(f0.x); v[1]=bf16b(f0.y); v[2]=bf16b(f0.z); v[3]=bf16b(f0.w);
  v[4]=bf16b(f1.x); v[5]=bf16b(f1.y); v[6]=bf16b(f1.z); v[7]=bf16b(f1.w);
  return v;
}

// ---- rel transfer, optionally fused with the PREVIOUS layer's trailing LN.
template<bool PRE_LN>
__global__ void __launch_bounds__(256) k_rel_transfer(float* __restrict__ rel,
    const float* __restrict__ rtw, const float* __restrict__ rtb,
    const float* __restrict__ g, const float* __restrict__ b,
    const float* __restrict__ gp, const float* __restrict__ bp, int rows){
  __shared__ float xrow[4][DD];
  float* xl = xrow[threadIdx.x >> 6];
  const int lane = threadIdx.x & 63;
  int wave = (int)((blockIdx.x * blockDim.x + threadIdx.x) >> 6);
  if (wave >= rows) return;
  int row = __builtin_amdgcn_readfirstlane(wave);
  float* x = rel + (size_t)row * DD;
  float t0 = x[lane], t1 = x[64 + lane];
  if (PRE_LN){
    float mu = wave_sum(t0 + t1) * (1.0f/128.0f);
    float e0 = t0 - mu, e1 = t1 - mu;
    float var = wave_sum(e0*e0 + e1*e1) * (1.0f/128.0f);
    float rs = rsqrtf(var + LNEPS);
    t0 = e0 * rs * gp[lane]      + bp[lane];
    t1 = e1 * rs * gp[64 + lane] + bp[64 + lane];
  }
  xl[lane] = t0; xl[64 + lane] = t1;
  float y0 = 0.f, y1 = 0.f;
#pragma unroll 4
  for (int d = 0; d < DD; ++d){
    float xd = xl[d];
    y0 = fmaf(xd, rtw[d*DD + lane],      y0);
    y1 = fmaf(xd, rtw[d*DD + 64 + lane], y1);
  }
  float u0 = t0 + fmaxf(y0 + rtb[lane],      0.f);
  float u1 = t1 + fmaxf(y1 + rtb[64 + lane], 0.f);
  float mu = wave_sum(u0 + u1) * (1.0f/128.0f);
  float e0 = u0 - mu, e1 = u1 - mu;
  float var = wave_sum(e0*e0 + e1*e1) * (1.0f/128.0f);
  float rs = rsqrtf(var + LNEPS);
  x[lane]      = e0 * rs * g[lane]      + b[lane];
  x[64 + lane] = e1 * rs * g[64 + lane] + b[64 + lane];
}

// ---- prep bf16 B-fragments from k-major weight W[K=128][C] (ldc = C)
__global__ void __launch_bounds__(256) k_prep_bfrag_km(const float* __restrict__ W,
    short* __restrict__ out, int C, int ldc){
  int idx = blockIdx.x * blockDim.x + threadIdx.x;
  int total = (C >> 4) * 4 * 64;
  if (idx >= total) return;
  int lane = idx & 63, ks = (idx >> 6) & 3, ct = idx >> 8;
  int k = ks*32 + ((lane >> 4) << 3);
  int c = (ct << 4) + (lane & 15);
  short8 v;
#pragma unroll
  for (int j = 0; j < 8; ++j) v[j] = bf16b(W[(size_t)(k + j)*ldc + c]);
  *reinterpret_cast<short8*>(out + (size_t)idx * 8) = v;
}

// ---- prep bf16 B-fragments from c-major weight W[Nc][128] (PyTorch [out,in])
__global__ void __launch_bounds__(256) k_prep_bfrag(const float* __restrict__ W,
    short* __restrict__ out, int Nc){
  int idx = blockIdx.x * blockDim.x + threadIdx.x;
  int total = (Nc >> 4) * 4 * 64;
  if (idx >= total) return;
  int lane = idx & 63, ks = (idx >> 6) & 3, ct = idx >> 8;
  int k = ks*32 + ((lane >> 4) << 3);
  int c = (ct << 4) + (lane & 15);
  const float* src = W + (size_t)c * DD + k;
  short8 v;
#pragma unroll
  for (int j = 0; j < 8; ++j) v[j] = bf16b(src[j]);
  *reinterpret_cast<short8*>(out + (size_t)idx * 8) = v;
}

// ---- MFMA projection + fused bf16 gather-table build (layer-0 N + rel tables)
__global__ void __launch_bounds__(256) k_proj_gt(const float* __restrict__ X,
    const short* __restrict__ Bf, unsigned short* __restrict__ GT, int rows){
  const int lane = threadIdx.x & 63;
  int wave = (int)((blockIdx.x * blockDim.x + threadIdx.x) >> 6);
  int r0 = wave * 16;
  if (r0 >= rows) return;
  if (r0 + 16 > rows) r0 = rows - 16;
  r0 = __builtin_amdgcn_readfirstlane(r0);
  const int arow = lane & 15;
  const int koff = (lane >> 4) << 3;
  short8 ax[4];
#pragma unroll
  for (int ks = 0; ks < 4; ++ks){
    ax[ks] = ld_frag_f32(X + (size_t)(r0 + arow) * DD + ks*32 + koff);
    *reinterpret_cast<short8*>((short*)GT + (size_t)(r0 + arow) * GTS + 64 + ks*32 + koff) = ax[ks];
  }
  f32x4 acc[4];
#pragma unroll
  for (int ct = 0; ct < 4; ++ct){
    acc[ct] = (f32x4)0.f;
#pragma unroll
    for (int ks = 0; ks < 4; ++ks){
      short8 bw = *reinterpret_cast<const short8*>(Bf + ((size_t)(ct*4 + ks)*64 + lane)*8);
      acc[ct] = __builtin_amdgcn_mfma_f32_16x16x32_bf16(ax[ks], bw, acc[ct], 0, 0, 0);
    }
  }
#pragma unroll
  for (int ct = 0; ct < 4; ++ct){
    int col = ct*16 + (lane & 15);
#pragma unroll
    for (int reg = 0; reg < 4; ++reg){
      int row = r0 + ((lane >> 4) << 2) + reg;
      ((short*)GT)[(size_t)row*GTS + col] = bf16b(acc[ct][reg]);
    }
  }
}

// ---- qr[b,:] = rel[q_rel[b]+b*Rp1,:] @ Wqr + bias
__global__ void __launch_bounds__(256) k_projq(const float* __restrict__ rel,
    const float* __restrict__ Wqr, const float* __restrict__ bias,
    const int* __restrict__ q_rel, float* __restrict__ out, int Bc, int Rp1){
  const int lane = threadIdx.x & 63;
  int wave = (int)((blockIdx.x * blockDim.x + threadIdx.x) >> 6);
  if (wave >= Bc) return;
  int b = __builtin_amdgcn_readfirstlane(wave);
  int f = __builtin_amdgcn_readfirstlane(q_rel[b] + b * Rp1);
  const float* x = rel + (size_t)f * DD;
  float a = 0.f;
#pragma unroll 4
  for (int d = 0; d < DD; ++d) a = fmaf(x[d], Wqr[d*AA + lane], a);
  out[(size_t)b*AA + lane] = a + bias[lane];
}

// ================= CSR build (once per call; obj constant across layers) ====
__global__ void __launch_bounds__(256) k_hist(const int* __restrict__ obj, int* __restrict__ deg, int E){
  int idx = blockIdx.x * blockDim.x + threadIdx.x;
  if (idx < E) atomicAdd(&deg[obj[idx]], 1);
}

__global__ void __launch_bounds__(1024) k_scan1(const int* __restrict__ deg,
    int* __restrict__ row_start, int* __restrict__ bsum, int n){
  __shared__ int sm[1024];
  int t = threadIdx.x;
  int i = blockIdx.x * 1024 + t;
  int v = (i < n) ? deg[i] : 0;
  sm[t] = v; __syncthreads();
#pragma unroll
  for (int off = 1; off < 1024; off <<= 1){
    int x = (t >= off) ? sm[t - off] : 0;
    __syncthreads();
    sm[t] += x;
    __syncthreads();
  }
  if (i < n) row_start[i] = sm[t] - v;
  if (t == 1023) bsum[blockIdx.x] = sm[1023];
}

__global__ void __launch_bounds__(1024) k_scan2(int* __restrict__ bsum, int nb){
  __shared__ int sm[1024];
  int t = threadIdx.x;
  int v = (t < nb) ? bsum[t] : 0;
  sm[t] = v; __syncthreads();
#pragma unroll
  for (int off = 1; off < 1024; off <<= 1){
    int x = (t >= off) ? sm[t - off] : 0;
    __syncthreads();
    sm[t] += x;
    __syncthreads();
  }
  if (t < nb) bsum[t] = sm[t] - v;
}

__global__ void __launch_bounds__(256) k_scan3(int* __restrict__ row_start,
    const int* __restrict__ bsum, int n, int E){
  int i = blockIdx.x * blockDim.x + threadIdx.x;
  if (i < n) row_start[i] += bsum[i >> 10];
  if (i == 0) row_start[n] = E;
}

// ---- scatter PACKED edge records into CSR order: rec = s | f<<17 | b<<28
__global__ void __launch_bounds__(256) k_scatter_edges(const int* __restrict__ obj,
    const int* __restrict__ sub, const int* __restrict__ bidx,
    const int* __restrict__ reli, const int* __restrict__ row_start,
    int* __restrict__ cursor, unsigned int* __restrict__ ER, int E, int Rp1){
  int e = blockIdx.x * blockDim.x + threadIdx.x;
  if (e < E){
    int o = obj[e];
    int pos = row_start[o] + atomicAdd(&cursor[o], 1);
    int bb = bidx[e];
    unsigned rec = (unsigned)sub[e] | ((unsigned)(reli[e] + bb * Rp1) << 17)
                 | ((unsigned)bb << 28);
    ER[pos] = rec;
  }
}

// ---- CSR edge kernel over packed records (round-9 version, unchanged)
__global__ void __launch_bounds__(256) k_edge_csr4(
    const unsigned short* __restrict__ GT, const unsigned short* __restrict__ RT,
    const float* __restrict__ qr,
    const float* __restrict__ wal, const float* __restrict__ walb_p,
    const unsigned int* __restrict__ ER, const int* __restrict__ row_start,
    float* __restrict__ agg, int Nn){
  const int lane = threadIdx.x & 63;
  const int g = lane >> 4;
  const int t = lane & 15;
  int wave = (int)((blockIdx.x * blockDim.x + threadIdx.x) >> 6);
  if (wave >= Nn) return;
  int o = __builtin_amdgcn_readfirstlane(wave);
  const int s0 = __builtin_amdgcn_readfirstlane(row_start[o]);
  const int s1 = __builtin_amdgcn_readfirstlane(row_start[o + 1]);
  const float4 wa4 = *reinterpret_cast<const float4*>(wal + t*4);
  const float wb = walb_p[0];
  float acc[8];
#pragma unroll
  for (int i = 0; i < 8; ++i) acc[i] = 0.f;
  for (int base = s0; base < s1; base += 8){
    int pA = base + g;
    int pB = base + g + 4;
    bool vA = pA < s1, vB = pB < s1;
    unsigned eA = ER[vA ? pA : s0];
    unsigned eB = ER[vB ? pB : s0];
    int sA = eA & 0x1FFFF, fA = (eA >> 17) & 0x7FF, bA = eA >> 28;
    int sB = eB & 0x1FFFF, fB = (eB >> 17) & 0x7FF, bB = eB >> 28;
    const unsigned short* gsA = GT + (size_t)sA * GTS;
    const unsigned short* rfA = RT + (size_t)fA * GTS;
    const unsigned short* gsB = GT + (size_t)sB * GTS;
    const unsigned short* rfB = RT + (size_t)fB * GTS;
    uint2 pgA = *reinterpret_cast<const uint2*>(gsA + t*4);
    uint2 prA = *reinterpret_cast<const uint2*>(rfA + t*4);
    float4 q4A = *reinterpret_cast<const float4*>(qr + (size_t)bA*AA + t*4);
    uint4 xgA = *reinterpret_cast<const uint4*>(gsA + 64 + t*8);
    uint4 xrA = *reinterpret_cast<const uint4*>(rfA + 64 + t*8);
    uint2 pgB = *reinterpret_cast<const uint2*>(gsB + t*4);
    uint2 prB = *reinterpret_cast<const uint2*>(rfB + t*4);
    float4 q4B = *reinterpret_cast<const float4*>(qr + (size_t)bB*AA + t*4);
    uint4 xgB = *reinterpret_cast<const uint4*>(gsB + 64 + t*8);
    uint4 xrB = *reinterpret_cast<const uint4*>(rfB + 64 + t*8);
    float pA0 = b2f_lo(pgA.x) + b2f_lo(prA.x) + q4A.x;
    float pA1 = b2f_hi(pgA.x) + b2f_hi(prA.x) + q4A.y;
    float pA2 = b2f_lo(pgA.y) + b2f_lo(prA.y) + q4A.z;
    float pA3 = b2f_hi(pgA.y) + b2f_hi(prA.y) + q4A.w;
    float dotA = rrelu_f(pA0)*wa4.x + rrelu_f(pA1)*wa4.y
               + rrelu_f(pA2)*wa4.z + rrelu_f(pA3)*wa4.w;
    float pB0 = b2f_lo(pgB.x) + b2f_lo(prB.x) + q4B.x;
    float pB1 = b2f_hi(pgB.x) + b2f_hi(prB.x) + q4B.y;
    float pB2 = b2f_lo(pgB.y) + b2f_lo(prB.y) + q4B.z;
    float pB3 = b2f_hi(pgB.y) + b2f_hi(prB.y) + q4B.w;
    float dotB = rrelu_f(pB0)*wa4.x + rrelu_f(pB1)*wa4.y
               + rrelu_f(pB2)*wa4.z + rrelu_f(pB3)*wa4.w;
#pragma unroll
    for (int off = 1; off < 16; off <<= 1){
      dotA += __shfl_xor(dotA, off, 64);
      dotB += __shfl_xor(dotB, off, 64);
    }
    float alA = vA ? sigm(dotA + wb) : 0.f;
    float alB = vB ? sigm(dotB + wb) : 0.f;
    acc[0] = fmaf(alA, b2f_lo(xgA.x) + b2f_lo(xrA.x), fmaf(alB, b2f_lo(xgB.x) + b2f_lo(xrB.x), acc[0]));
    acc[1] = fmaf(alA, b2f_hi(xgA.x) + b2f_hi(xrA.x), fmaf(alB, b2f_hi(xgB.x) + b2f_hi(xrB.x), acc[1]));
    acc[2] = fmaf(alA, b2f_lo(xgA.y) + b2f_lo(xrA.y), fmaf(alB, b2f_lo(xgB.y) + b2f_lo(xrB.y), acc[2]));
    acc[3] = fmaf(alA, b2f_hi(xgA.y) + b2f_hi(xrA.y), fmaf(alB, b2f_hi(xgB.y) + b2f_hi(xrB.y), acc[3]));
    acc[4] = fmaf(alA, b2f_lo(xgA.z) + b2f_lo(xrA.z), fmaf(alB, b2f_lo(xgB.z) + b2f_lo(xrB.z), acc[4]));
    acc[5] = fmaf(alA, b2f_hi(xgA.z) + b2f_hi(xrA.z), fmaf(alB, b2f_hi(xgB.z) + b2f_hi(xrB.z), acc[5]));
    acc[6] = fmaf(alA, b2f_lo(xgA.w) + b2f_lo(xrA.w), fmaf(alB, b2f_lo(xgB.w) + b2f_lo(xrB.w), acc[6]));
    acc[7] = fmaf(alA, b2f_hi(xgA.w) + b2f_hi(xrA.w), fmaf(alB, b2f_hi(xgB.w) + b2f_hi(xrB.w), acc[7]));
  }
#pragma unroll
  for (int i = 0; i < 8; ++i){
    acc[i] += __shfl_xor(acc[i], 16, 64);
    acc[i] += __shfl_xor(acc[i], 32, 64);
  }
  if (g == 0){
    float4 v0 = make_float4(acc[0], acc[1], acc[2], acc[3]);
    float4 v1 = make_float4(acc[4], acc[5], acc[6], acc[7]);
    *reinterpret_cast<float4*>(agg + (size_t)o*DD + t*8)     = v0;
    *reinterpret_cast<float4*>(agg + (size_t)o*DD + t*8 + 4) = v1;
  }
}

// ---- FUSED: H = gru(x = LN(rrelu(AGG@Wh)), h = H), in place.
// r11's 9-barrier merged ih+hh staging, but xtile ALIASES wbuf[0] (xtile is
// dead after the ax read; stage(0) issued after it) -> LDS 48KB -> 3 blk/CU.
// H written to global every unit (no register buffering -> no scratch);
// PROJ/SCORE epilogue re-reads the wave's own H rows from global (L2-hot).
template<bool HAS_H, bool PROJ, bool SCORE>
__global__ void __launch_bounds__(256) k_whlngru(const float* __restrict__ AGG,
    float* H, const short* __restrict__ Bwh, const short* __restrict__ Bih,
    const short* __restrict__ Bhh, const float* __restrict__ lng,
    const float* __restrict__ lnb, const float* __restrict__ bih,
    const float* __restrict__ bhh,
    const short* __restrict__ Bproj, unsigned short* __restrict__ GT,
    const float* __restrict__ wf, const int* __restrict__ nbp,
    const int* __restrict__ nep, float* __restrict__ scores,
    int* __restrict__ winner, int NENT, int rows){
  constexpr int FPW = HAS_H ? 6 : 3;        // frags staged per wave per unit
  __shared__ short wbuf[2][24 * 512];       // 48KB total; wbuf[0] doubles as xtile
  short* xl = &wbuf[0][(threadIdx.x >> 6) * 16 * XPAD];  // 4*2176=8704 <= 12288 ok
  const int lane = threadIdx.x & 63;
  const int wib  = threadIdx.x >> 6;
  int wave = (int)((blockIdx.x * blockDim.x + threadIdx.x) >> 6);
  const bool live = (wave * 16 < rows);
  int r0 = live ? wave * 16 : 0;
  if (r0 + 16 > rows) r0 = rows - 16;
  r0 = __builtin_amdgcn_readfirstlane(r0);
  const int arow = lane & 15;
  const int koff = (lane >> 4) << 3;
  const int lrbase = (lane >> 4) << 2;

  // cooperative stage of unit u (= col-tile u) into wbuf[par]
  auto stage = [&](int u, int par){
#pragma unroll
    for (int jj = 0; jj < FPW; ++jj){
      int j = wib * FPW + jj;                 // 0..(12*FPW/3 -1)
      int jl = (j < 12) ? j : j - 12;
      const short* src = (HAS_H && j >= 12) ? Bhh : Bih;
      int gfrag = (jl >> 2) * 32 + u * 4 + (jl & 3);
      *reinterpret_cast<short8*>(&wbuf[par][j * 512 + lane * 8]) =
          *reinterpret_cast<const short8*>(src + (size_t)gfrag * 512 + lane * 8);
    }
  };

  // ---- phase 1: acc[ct] = (AGG @ Wh) tile, rrelu (Bwh from global)
  short8 aa[4];
#pragma unroll
  for (int ks = 0; ks < 4; ++ks)
    aa[ks] = ld_frag_f32(AGG + (size_t)(r0 + arow) * DD + ks*32 + koff);
  f32x4 acc[8];
#pragma unroll
  for (int ct = 0; ct < 8; ++ct){
    acc[ct] = (f32x4)0.f;
#pragma unroll
    for (int ks = 0; ks < 4; ++ks){
      short8 bw = *reinterpret_cast<const short8*>(Bwh + ((size_t)(ct*4 + ks)*64 + lane)*8);
      acc[ct] = __builtin_amdgcn_mfma_f32_16x16x32_bf16(aa[ks], bw, acc[ct], 0, 0, 0);
    }
  }
#pragma unroll
  for (int ct = 0; ct < 8; ++ct)
#pragma unroll
    for (int reg = 0; reg < 4; ++reg) acc[ct][reg] = rrelu_f(acc[ct][reg]);

  // ---- in-wave LayerNorm per row, write bf16 X-tile to per-wave LDS (=wbuf[0] alias)
  float mu[4], rs[4];
#pragma unroll
  for (int reg = 0; reg < 4; ++reg){
    float s = 0.f, ss = 0.f;
#pragma unroll
    for (int ct = 0; ct < 8; ++ct){ float v = acc[ct][reg]; s += v; ss += v*v; }
    s = red16(s); ss = red16(ss);
    float m = s * (1.0f/128.0f);
    float var = ss * (1.0f/128.0f) - m*m;
    mu[reg] = m;
    rs[reg] = rsqrtf(var + LNEPS);
  }
#pragma unroll
  for (int ct = 0; ct < 8; ++ct){
    int col = ct*16 + (lane & 15);
    float gv = lng[col], bv = lnb[col];
#pragma unroll
    for (int reg = 0; reg < 4; ++reg){
      float xn = (acc[ct][reg] - mu[reg]) * rs[reg] * gv + bv;
      xl[(lrbase + reg) * XPAD + col] = bf16b(xn);
    }
  }

  // ---- A-fragments for phase 2 (after this, xtile/wbuf[0] is dead)
  short8 ax[4], ah8[4];
#pragma unroll
  for (int ks = 0; ks < 4; ++ks)
    ax[ks] = *reinterpret_cast<const short8*>(&xl[arow * XPAD + ks*32 + koff]);
  if (HAS_H){
#pragma unroll
    for (int ks = 0; ks < 4; ++ks)
      ah8[ks] = ld_frag_f32(H + (size_t)(r0 + arow) * DD + ks*32 + koff);
  }

  stage(0, 1);       // unit 0 -> wbuf[1] (wbuf[0] still held xtile until here)
  __syncthreads();   // wbuf[1] ready; xtile reads complete everywhere

  // ---- phase 2: GRU; unit u reads wbuf[(u+1)&1], stages u+1 into wbuf[u&1]
#pragma unroll
  for (int u = 0; u < 8; ++u){
    if (u + 1 < 8) stage(u + 1, u & 1);
    const short* wb = wbuf[(u + 1) & 1];
    f32x4 air = (f32x4)0.f, aiz = (f32x4)0.f, ain = (f32x4)0.f;
    f32x4 ahr = (f32x4)0.f, ahz = (f32x4)0.f, ahn = (f32x4)0.f;
#pragma unroll
    for (int ks = 0; ks < 4; ++ks){
      short8 b0 = *reinterpret_cast<const short8*>(&wb[(0*4 + ks)*512 + lane*8]);
      short8 b1 = *reinterpret_cast<const short8*>(&wb[(1*4 + ks)*512 + lane*8]);
      short8 b2 = *reinterpret_cast<const short8*>(&wb[(2*4 + ks)*512 + lane*8]);
      air = __builtin_amdgcn_mfma_f32_16x16x32_bf16(ax[ks], b0, air, 0, 0, 0);
      aiz = __builtin_amdgcn_mfma_f32_16x16x32_bf16(ax[ks], b1, aiz, 0, 0, 0);
      ain = __builtin_amdgcn_mfma_f32_16x16x32_bf16(ax[ks], b2, ain, 0, 0, 0);
      if (HAS_H){
        short8 c0 = *reinterpret_cast<const short8*>(&wb[(12 + 0*4 + ks)*512 + lane*8]);
        short8 c1 = *reinterpret_cast<const short8*>(&wb[(12 + 1*4 + ks)*512 + lane*8]);
        short8 c2 = *reinterpret_cast<const short8*>(&wb[(12 + 2*4 + ks)*512 + lane*8]);
        ahr = __builtin_amdgcn_mfma_f32_16x16x32_bf16(ah8[ks], c0, ahr, 0, 0, 0);
        ahz = __builtin_amdgcn_mfma_f32_16x16x32_bf16(ah8[ks], c1, ahz, 0, 0, 0);
        ahn = __builtin_amdgcn_mfma_f32_16x16x32_bf16(ah8[ks], c2, ahn, 0, 0, 0);
      }
    }
    {
      int col = u*16 + (lane & 15);
      float bi_r = bih[col], bi_z = bih[128 + col], bi_n = bih[256 + col];
      float bh_r = bhh[col], bh_z = bhh[128 + col], bh_n = bhh[256 + col];
#pragma unroll
      for (int reg = 0; reg < 4; ++reg){
        int row = r0 + lrbase + reg;
        float gi_r = air[reg] + bi_r;
        float gi_z = aiz[reg] + bi_z;
        float gi_n = ain[reg] + bi_n;
        float gh_r = (HAS_H ? ahr[reg] : 0.f) + bh_r;
        float gh_z = (HAS_H ? ahz[reg] : 0.f) + bh_z;
        float gh_n = (HAS_H ? ahn[reg] : 0.f) + bh_n;
        float rg = sigm(gi_r + gh_r);
        float zg = sigm(gi_z + gh_z);
        float ng = fast_tanh(gi_n + rg * gh_n);
        float hp = HAS_H ? H[(size_t)row * DD + col] : 0.f;
        float hv = (1.f - zg) * ng + zg * hp;
        if (live) H[(size_t)row * DD + col] = hv;
      }
    }
    __syncthreads();
  }

  // ---- epilogue: fused next-layer projection / final score; H re-read from
  // global (same-wave rows, L2-hot, vmcnt-ordered).
  if (PROJ || SCORE){
    short8 hx[4];
#pragma unroll
    for (int ks = 0; ks < 4; ++ks)
      hx[ks] = ld_frag_f32(H + (size_t)(r0 + arow) * DD + ks*32 + koff);
    if (PROJ){
      if (live){
#pragma unroll
        for (int ks = 0; ks < 4; ++ks)
          *reinterpret_cast<short8*>((short*)GT + (size_t)(r0 + arow) * GTS + 64 + ks*32 + koff) = hx[ks];
      }
      f32x4 pacc[4];
#pragma unroll
      for (int ct = 0; ct < 4; ++ct){
        pacc[ct] = (f32x4)0.f;
#pragma unroll
        for (int ks = 0; ks < 4; ++ks){
          short8 bw = *reinterpret_cast<const short8*>(Bproj + ((size_t)(ct*4 + ks)*64 + lane)*8);
          pacc[ct] = __builtin_amdgcn_mfma_f32_16x16x32_bf16(hx[ks], bw, pacc[ct], 0, 0, 0);
        }
      }
      if (live){
#pragma unroll
        for (int ct = 0; ct < 4; ++ct){
          int col = ct*16 + (lane & 15);
#pragma unroll
          for (int reg = 0; reg < 4; ++reg){
            int row = r0 + lrbase + reg;
            ((short*)GT)[(size_t)row*GTS + col] = bf16b(pacc[ct][reg]);
          }
        }
      }
    }
    if (SCORE){
      float part = 0.f;
#pragma unroll
      for (int ks = 0; ks < 4; ++ks){
#pragma unroll
        for (int j = 0; j < 8; ++j)
          part = fmaf(b2f_s(hx[ks][j]), wf[ks*32 + koff + j], part);
      }
      part += __shfl_xor(part, 16, 64);
      part += __shfl_xor(part, 32, 64);
      if (live && (lane >> 4) == 0){
        int row = r0 + arow;
        scores[row] = part;
        int slot = nbp[row] * NENT + nep[row];
        atomicMax(&winner[slot], row);
      }
    }
  }
}

__global__ void __launch_bounds__(256) k_scatter(const float* __restrict__ scores,
    const int* __restrict__ winner, const int* __restrict__ nb, const int* __restrict__ ne,
    float* __restrict__ out, int rows, int NENT){
  int n = blockIdx.x * blockDim.x + threadIdx.x;
  if (n < rows){
    int slot = nb[n] * NENT + ne[n];
    if (winner[slot] == n) out[slot] = scores[n];
  }
}

extern "C" void kernel_launch(void* const* d_in, const int* in_sizes, int n_in,
                              void* d_out, int out_size, void* d_ws, size_t ws_size,
                              hipStream_t stream){
  const float* hidden0 = (const float*)d_in[0];
  const float* rel0    = (const float*)d_in[1];
  const int* batch_idx = (const int*)d_in[2];
  const int* rel_i     = (const int*)d_in[3];
  const int* sub       = (const int*)d_in[4];
  const int* obj       = (const int*)d_in[5];
  const int* q_rel     = (const int*)d_in[6];
  const int* nb        = (const int*)d_in[7];
  const int* ne        = (const int*)d_in[8];
  const float* Ws      = (const float*)d_in[9];
  const float* Wr      = (const float*)d_in[10];
  const float* Wqr_w   = (const float*)d_in[11];
  const float* Wqr_b   = (const float*)d_in[12];
  const float* Wal_w   = (const float*)d_in[13];
  const float* Wal_b   = (const float*)d_in[14];
  const float* Wh      = (const float*)d_in[15];
  const float* rt_w    = (const float*)d_in[16];
  const float* rt_b    = (const float*)d_in[17];
  const float* ln_g    = (const float*)d_in[18];
  const float* ln_b    = (const float*)d_in[19];
  const float* lnr_g   = (const float*)d_in[20];
  const float* lnr_b   = (const float*)d_in[21];
  const float* wih     = (const float*)d_in[22];
  const float* whh     = (const float*)d_in[23];
  const float* bih     = (const float*)d_in[24];
  const float* bhh     = (const float*)d_in[25];
  const float* wfin    = (const float*)d_in[26];

  const int N    = in_sizes[0] / DD;
  const int NR   = in_sizes[1] / DD;
  const int E    = in_sizes[2];
  const int Bc   = in_sizes[6];
  const int L    = in_sizes[14];
  const int Rp1  = NR / Bc;
  const int NENT = out_size / Bc;

  char* wsp = (char*)d_ws;
  auto alloc = [&](size_t bytes) -> void* {
    void* p = (void*)wsp;
    wsp += (bytes + 255) & ~(size_t)255;
    return p;
  };
  float* AGG     = (float*)alloc((size_t)N * DD * 4);
  float* HBUF    = (float*)alloc((size_t)N * DD * 4);
  float* rel_cur = (float*)alloc((size_t)NR * DD * 4);
  unsigned short* GT = (unsigned short*)alloc((size_t)N * GTS * 2);
  unsigned short* RT = (unsigned short*)alloc((size_t)NR * GTS * 2);
  float* qr      = (float*)alloc((size_t)Bc * AA * 4);
  short* Bih     = (short*)alloc((size_t)(GG/16) * 4 * 64 * 8 * 2);
  short* Bhh     = (short*)alloc((size_t)(GG/16) * 4 * 64 * 8 * 2);
  short* Bws     = (short*)alloc((size_t)L * 4 * 4 * 64 * 8 * 2);
  short* Bwr     = (short*)alloc((size_t)L * 4 * 4 * 64 * 8 * 2);
  short* Bwh     = (short*)alloc((size_t)L * 8 * 4 * 64 * 8 * 2);
  float* scores  = (float*)alloc((size_t)N * 4);
  int*   winner  = (int*)alloc((size_t)Bc * NENT * 4);
  int*   deg     = (int*)alloc((size_t)N * 4);
  int*   row_st  = (int*)alloc((size_t)(N + 1) * 4);
  int*   cursor  = (int*)alloc((size_t)N * 4);
  unsigned int* ER = (unsigned int*)alloc((size_t)E * 4);
  int*   bsum    = (int*)alloc((size_t)1024 * 4);
  (void)ws_size; (void)n_in;

  hipMemcpyAsync(rel_cur, rel0, (size_t)NR * DD * 4, hipMemcpyDeviceToDevice, stream);
  {
    int totg = (GG/16) * 4 * 64;
    k_prep_bfrag<<<(totg + 255)/256, 256, 0, stream>>>(wih, Bih, GG);
    k_prep_bfrag<<<(totg + 255)/256, 256, 0, stream>>>(whh, Bhh, GG);
    int tot64 = 4 * 4 * 64;          // C=64 fragments
    int tot128 = 8 * 4 * 64;         // C=128 fragments
    for (int i = 0; i < L; ++i){
      k_prep_bfrag_km<<<(tot64 + 255)/256, 256, 0, stream>>>(Ws + (size_t)i*DD*AA, Bws + (size_t)i*tot64*8, AA, AA);
      k_prep_bfrag_km<<<(tot64 + 255)/256, 256, 0, stream>>>(Wr + (size_t)i*DD*AA, Bwr + (size_t)i*tot64*8, AA, AA);
      k_prep_bfrag_km<<<(tot128 + 255)/256, 256, 0, stream>>>(Wh + (size_t)i*DD*DD, Bwh + (size_t)i*tot128*8, DD, DD);
    }
  }
  hipMemsetAsync(d_out, 0, (size_t)out_size * 4, stream);
  hipMemsetAsync(winner, 0xFF, (size_t)Bc * NENT * 4, stream);

  // ---- build CSR over obj with packed edge records (constant across layers)
  hipMemsetAsync(deg, 0, (size_t)N * 4, stream);
  hipMemsetAsync(cursor, 0, (size_t)N * 4, stream);
  k_hist<<<(E + 255)/256, 256, 0, stream>>>(obj, deg, E);
  {
    int nb1 = (N + 1023)/1024;
    k_scan1<<<nb1, 1024, 0, stream>>>(deg, row_st, bsum, N);
    k_scan2<<<1, 1024, 0, stream>>>(bsum, nb1);
    k_scan3<<<(N + 255)/256, 256, 0, stream>>>(row_st, bsum, N, E);
  }
  k_scatter_edges<<<(E + 255)/256, 256, 0, stream>>>(obj, sub, batch_idx, rel_i,
      row_st, cursor, ER, E, Rp1);

  auto blocks4 = [](int waves){ return (waves + 3) / 4; };
  const int tot64 = 4 * 4 * 64;
  const int tot128 = 8 * 4 * 64;

  for (int i = 0; i < L; ++i){
    if (i == 0)
      k_rel_transfer<false><<<blocks4(NR), 256, 0, stream>>>(rel_cur,
          rt_w + (size_t)i*DD*DD, rt_b + (size_t)i*DD,
          lnr_g + (size_t)i*DD, lnr_b + (size_t)i*DD,
          nullptr, nullptr, NR);
    else
      k_rel_transfer<true><<<blocks4(NR), 256, 0, stream>>>(rel_cur,
          rt_w + (size_t)i*DD*DD, rt_b + (size_t)i*DD,
          lnr_g + (size_t)i*DD, lnr_b + (size_t)i*DD,
          lnr_g + (size_t)(i-1)*DD, lnr_b + (size_t)(i-1)*DD, NR);
    if (i == 0)   // later layers: GT is produced by the previous whlngru (PROJ)
      k_proj_gt<<<blocks4((N+15)/16), 256, 0, stream>>>(hidden0, Bws, GT, N);
    k_proj_gt<<<blocks4((NR+15)/16), 256, 0, stream>>>(rel_cur, Bwr + (size_t)i*tot64*8, RT, NR);
    k_projq<<<blocks4(Bc), 256, 0, stream>>>(rel_cur, Wqr_w + (size_t)i*DD*AA,
        Wqr_b + (size_t)i*AA, q_rel, qr, Bc, Rp1);
    k_edge_csr4<<<blocks4(N), 256, 0, stream>>>(GT, RT, qr,
        Wal_w + (size_t)i*AA, Wal_b + i, ER, row_st, AGG, N);
    {
      int waves = (N + 15)/16;
      int blocks = blocks4(waves);
      const bool has_h = (i > 0);
      const bool proj  = (i + 1 < L);
      const bool score = (i == L - 1);
      const short* Bp = proj ? (Bws + (size_t)(i+1)*tot64*8) : nullptr;
      const float* lg = ln_g + (size_t)i*DD;
      const float* lb = ln_b + (size_t)i*DD;
      const short* Bw = Bwh + (size_t)i*tot128*8;
      if (!has_h && proj && !score)
        k_whlngru<false,true,false><<<blocks, 256, 0, stream>>>(AGG, HBUF, Bw, Bih, Bhh,
            lg, lb, bih, bhh, Bp, GT, wfin, nb, ne, scores, winner, NENT, N);
      else if (!has_h && !proj && score)
        k_whlngru<false,false,true><<<blocks, 256, 0, stream>>>(AGG, HBUF, Bw, Bih, Bhh,
            lg, lb, bih, bhh, Bp, GT, wfin, nb, ne, scores, winner, NENT, N);
      else if (has_h && proj && !score)
        k_whlngru<true,true,false><<<blocks, 256, 0, stream>>>(AGG, HBUF, Bw, Bih, Bhh,
            lg, lb, bih, bhh, Bp, GT, wfin, nb, ne, scores, winner, NENT, N);
      else
        k_whlngru<true,false,true><<<blocks, 256, 0, stream>>>(AGG, HBUF, Bw, Bih, Bhh,
            lg, lb, bih, bhh, Bp, GT, wfin, nb, ne, scores, winner, NENT, N);
    }
  }

  k_scatter<<<(N + 255)/256, 256, 0, stream>>>(scores, winner, nb, ne, (float*)d_out, N, NENT);
}